// Round 3
// baseline (795.676 us; speedup 1.0000x reference)
//
#include <hip/hip_runtime.h>
#include <stdint.h>

#define BATCH 4096
#define NJ 18
#define DIMM 512
#define HEADS 8
#define DEPTH 64
#define MROWS (BATCH*NJ)               // 73728
#define ATT_OFF ((size_t)MROWS*DIMM)   // start of att in d_out (floats)

typedef __bf16 bf16_t;
typedef __bf16 bf16x8 __attribute__((ext_vector_type(8)));
typedef float f32x4 __attribute__((ext_vector_type(4)));
typedef _Float16 f16_t;
typedef _Float16 f16x2 __attribute__((ext_vector_type(2)));
typedef _Float16 f16x4 __attribute__((ext_vector_type(4)));
typedef _Float16 f16x8 __attribute__((ext_vector_type(8)));

// ---------------------------------------------------------------------------
// Kernel 0: transpose + hi/lo bf16 split of the 4 weights: W[k][n] -> Th/Tl[n][k]
// W = Th + Tl to ~2^-17 relative. grid (8,8,4), block 256.
// ---------------------------------------------------------------------------
__global__ __launch_bounds__(256) void split_w_kernel(
    const float* __restrict__ W0, const float* __restrict__ W1,
    const float* __restrict__ W2, const float* __restrict__ W3,
    bf16_t* __restrict__ Th0, bf16_t* __restrict__ Tl0,
    bf16_t* __restrict__ Th1, bf16_t* __restrict__ Tl1,
    bf16_t* __restrict__ Th2, bf16_t* __restrict__ Tl2,
    bf16_t* __restrict__ Th3, bf16_t* __restrict__ Tl3)
{
    const float* W = blockIdx.z == 0 ? W0 : blockIdx.z == 1 ? W1 : blockIdx.z == 2 ? W2 : W3;
    bf16_t* Th = blockIdx.z == 0 ? Th0 : blockIdx.z == 1 ? Th1 : blockIdx.z == 2 ? Th2 : Th3;
    bf16_t* Tl = blockIdx.z == 0 ? Tl0 : blockIdx.z == 1 ? Tl1 : blockIdx.z == 2 ? Tl2 : Tl3;
    __shared__ float ld[64][65];
    int k0 = blockIdx.y * 64, n0 = blockIdx.x * 64;
    int tid = threadIdx.x;
    #pragma unroll
    for (int it = 0; it < 16; ++it) {
        int idx = tid + it * 256;
        int kk = idx >> 6, nn = idx & 63;
        ld[kk][nn] = W[(size_t)(k0 + kk) * DIMM + n0 + nn];
    }
    __syncthreads();
    #pragma unroll
    for (int it = 0; it < 16; ++it) {
        int idx = tid + it * 256;
        int nn = idx >> 6, kk = idx & 63;
        float w = ld[kk][nn];
        bf16_t h = (bf16_t)w;
        bf16_t l = (bf16_t)(w - (float)h);
        Th[(size_t)(n0 + nn) * DIMM + k0 + kk] = h;
        Tl[(size_t)(n0 + nn) * DIMM + k0 + kk] = l;
    }
}

// ---------------------------------------------------------------------------
// f32-emulated GEMM via bf16x3: C = A @ W,  W pre-split (Bth + Btl)[n][k].
// A split on the fly into Ah+Al bf16.  acc += Ah*Bh + Ah*Bl + Al*Bh.
// 128x128 tile, BK=32, 4 waves (2x2), per-wave 64x64 via 4x4 16x16x32 MFMA.
// MODE 0: A f32 -> C f16 (projections).  MODE 1: A f16 -> C f32 + bias (final).
// ---------------------------------------------------------------------------
template <int MODE>
__global__ __launch_bounds__(256) void gemm3_kernel(
    const void* __restrict__ Aparm,
    const bf16_t* __restrict__ Bth, const bf16_t* __restrict__ Btl,
    void* __restrict__ Cparm, const float* __restrict__ bias)
{
    __shared__ __align__(16) bf16_t Ah[128 * 40];
    __shared__ __align__(16) bf16_t Al[128 * 40];
    __shared__ __align__(16) bf16_t Bh[128 * 40];
    __shared__ __align__(16) bf16_t Bl[128 * 40];
    const int tid = threadIdx.x;
    const int lane = tid & 63;
    const int wv = tid >> 6;
    const int wm = wv >> 1, wn = wv & 1;
    const int bm = blockIdx.y * 128, bn = blockIdx.x * 128;
    const int l15 = lane & 15, lg = lane >> 4;

    f32x4 acc[4][4] = {};

    for (int ks = 0; ks < DIMM / 32; ++ks) {
        const int k0 = ks * 32;
        __syncthreads();
        #pragma unroll
        for (int r = 0; r < 2; ++r) {
            int c = tid + r * 256;            // 512 chunks of 8 elements
            int row = c >> 2, kc = c & 3;
            float x[8];
            if constexpr (MODE == 0) {
                const float* A = (const float*)Aparm;
                const f32x4* p = (const f32x4*)(A + (size_t)(bm + row) * DIMM + k0 + kc * 8);
                f32x4 a0 = p[0], a1 = p[1];
                x[0]=a0[0]; x[1]=a0[1]; x[2]=a0[2]; x[3]=a0[3];
                x[4]=a1[0]; x[5]=a1[1]; x[6]=a1[2]; x[7]=a1[3];
            } else {
                const f16_t* A = (const f16_t*)Aparm;
                f16x8 a = *(const f16x8*)(A + (size_t)(bm + row) * DIMM + k0 + kc * 8);
                #pragma unroll
                for (int e = 0; e < 8; ++e) x[e] = (float)a[e];
            }
            bf16x8 h8, l8;
            #pragma unroll
            for (int e = 0; e < 8; ++e) {
                bf16_t hh = (bf16_t)x[e];
                h8[e] = hh;
                l8[e] = (bf16_t)(x[e] - (float)hh);
            }
            *(bf16x8*)(&Ah[row * 40 + kc * 8]) = h8;
            *(bf16x8*)(&Al[row * 40 + kc * 8]) = l8;
            bf16x8 bh = *(const bf16x8*)(Bth + (size_t)(bn + row) * DIMM + k0 + kc * 8);
            bf16x8 bl = *(const bf16x8*)(Btl + (size_t)(bn + row) * DIMM + k0 + kc * 8);
            *(bf16x8*)(&Bh[row * 40 + kc * 8]) = bh;
            *(bf16x8*)(&Bl[row * 40 + kc * 8]) = bl;
        }
        __syncthreads();
        bf16x8 afh[4], afl[4], bfh[4], bfl[4];
        #pragma unroll
        for (int mi = 0; mi < 4; ++mi) {
            afh[mi] = *(const bf16x8*)(&Ah[(wm * 64 + mi * 16 + l15) * 40 + lg * 8]);
            afl[mi] = *(const bf16x8*)(&Al[(wm * 64 + mi * 16 + l15) * 40 + lg * 8]);
        }
        #pragma unroll
        for (int ni = 0; ni < 4; ++ni) {
            bfh[ni] = *(const bf16x8*)(&Bh[(wn * 64 + ni * 16 + l15) * 40 + lg * 8]);
            bfl[ni] = *(const bf16x8*)(&Bl[(wn * 64 + ni * 16 + l15) * 40 + lg * 8]);
        }
        #pragma unroll
        for (int mi = 0; mi < 4; ++mi)
            #pragma unroll
            for (int ni = 0; ni < 4; ++ni) {
                acc[mi][ni] = __builtin_amdgcn_mfma_f32_16x16x32_bf16(
                    afh[mi], bfh[ni], acc[mi][ni], 0, 0, 0);
                acc[mi][ni] = __builtin_amdgcn_mfma_f32_16x16x32_bf16(
                    afh[mi], bfl[ni], acc[mi][ni], 0, 0, 0);
                acc[mi][ni] = __builtin_amdgcn_mfma_f32_16x16x32_bf16(
                    afl[mi], bfh[ni], acc[mi][ni], 0, 0, 0);
            }
    }

    // epilogue: C/D layout col = lane&15, row = (lane>>4)*4 + reg  [HW-verified]
    #pragma unroll
    for (int mi = 0; mi < 4; ++mi) {
        #pragma unroll
        for (int ni = 0; ni < 4; ++ni) {
            int col = bn + wn * 64 + ni * 16 + l15;
            int rowb = bm + wm * 64 + mi * 16 + lg * 4;
            f32x4 v = acc[mi][ni];
            if constexpr (MODE == 1) {
                float* C = (float*)Cparm;
                float bv = bias[col];
                #pragma unroll
                for (int r = 0; r < 4; ++r)
                    C[(size_t)(rowb + r) * DIMM + col] = v[r] + bv;
            } else {
                f16_t* C = (f16_t*)Cparm;
                #pragma unroll
                for (int r = 0; r < 4; ++r)
                    C[(size_t)(rowb + r) * DIMM + col] = (f16_t)v[r];
            }
        }
    }
}

// ---------------------------------------------------------------------------
// Attention core: one block (256 thr) per sample b. All math f32; q/k/v f16.
//   rel_bias[b,i,j] = t4[i][map[i][j]],  t4[i][c] = dot64(sum_h kh[i], rel_k[c])
//   dots=(QK^T+rel_bias)*0.125; att=softmax; write att f32; ao = att@V + bucket(rel_v)
//   ao aliases vh: all v reads go to LDS before barrier, writes after. Safe.
// ---------------------------------------------------------------------------
__global__ __launch_bounds__(256) void attn_kernel(
    const f16_t* __restrict__ qh, const f16_t* __restrict__ kh,
    const f16_t* __restrict__ vh,
    const float* __restrict__ rel_k, const float* __restrict__ rel_v,
    const int* __restrict__ jmap,
    float* __restrict__ att_out, f16_t* __restrict__ ao)
{
    const int b = blockIdx.x;
    const int tid = threadIdx.x;
    __shared__ __align__(16) f16_t q_s[NJ * DIMM];
    __shared__ __align__(16) f16_t k_s[NJ * DIMM];
    __shared__ __align__(16) f16_t v_s[NJ * DIMM];
    __shared__ float relk_s[4 * DEPTH];
    __shared__ float relv_s[4 * DEPTH];
    __shared__ int map_s[NJ * NJ];
    __shared__ float ksum_s[NJ * DEPTH];
    __shared__ float t4_s[NJ * 4];
    __shared__ float att_s[HEADS * NJ * NJ];
    __shared__ float sb_s[HEADS * NJ * 4];

    const size_t base = (size_t)b * (NJ * DIMM);
    const uint4* qg = (const uint4*)(qh + base);
    const uint4* kg = (const uint4*)(kh + base);
    const uint4* vg = (const uint4*)(vh + base);
    for (int c = tid; c < 3 * 1152; c += 256) {       // 1152 = 18*512*2B/16B
        int t = c / 1152, e = c - t * 1152;
        uint4 val = (t == 0 ? qg : t == 1 ? kg : vg)[e];
        ((uint4*)(t == 0 ? q_s : t == 1 ? k_s : v_s))[e] = val;
    }
    relk_s[tid] = rel_k[tid & 255];
    relv_s[tid] = rel_v[tid & 255];
    for (int e = tid; e < NJ * NJ; e += 256) map_s[e] = jmap[e];   // 324 > 256: strided!
    __syncthreads();

    for (int e = tid; e < NJ * DEPTH; e += 256) {
        int i = e >> 6, dd = e & 63;
        float s = 0.f;
        #pragma unroll
        for (int h = 0; h < HEADS; ++h) s += (float)k_s[i * DIMM + h * DEPTH + dd];
        ksum_s[e] = s;
    }
    __syncthreads();
    if (tid < NJ * 4) {
        int i = tid >> 2, c = tid & 3;
        float s = 0.f;
        #pragma unroll
        for (int dd = 0; dd < DEPTH; ++dd) s += ksum_s[i * DEPTH + dd] * relk_s[c * DEPTH + dd];
        t4_s[tid] = s;
    }
    __syncthreads();

    if (tid < HEADS * NJ) {
        const int h = tid / NJ, i = tid - (tid / NJ) * NJ;
        float dots[NJ];
        float m = -1e30f;
        const f16x4* qp = (const f16x4*)&q_s[i * DIMM + h * DEPTH];
        #pragma unroll
        for (int j = 0; j < NJ; ++j) {
            const f16x4* kp = (const f16x4*)&k_s[j * DIMM + h * DEPTH];
            float s = 0.f;
            #pragma unroll
            for (int t = 0; t < 16; ++t) {            // 64 elems, 4 per iter
                f16x4 a = qp[t], c4 = kp[t];
                s += (float)a[0] * (float)c4[0] + (float)a[1] * (float)c4[1]
                   + (float)a[2] * (float)c4[2] + (float)a[3] * (float)c4[3];
            }
            s += t4_s[i * 4 + map_s[i * NJ + j]];
            s *= 0.125f;
            dots[j] = s;
            m = fmaxf(m, s);
        }
        float sum = 0.f;
        #pragma unroll
        for (int j = 0; j < NJ; ++j) { dots[j] = __expf(dots[j] - m); sum += dots[j]; }
        const float inv = 1.f / sum;
        float s40 = 0.f, s41 = 0.f, s42 = 0.f, s43 = 0.f;
        #pragma unroll
        for (int j = 0; j < NJ; ++j) {
            float a = dots[j] * inv;
            att_s[(h * NJ + i) * NJ + j] = a;
            att_out[(((size_t)b * HEADS + h) * NJ + i) * NJ + j] = a;
            int c = map_s[i * NJ + j];
            s40 += (c == 0) ? a : 0.f;
            s41 += (c == 1) ? a : 0.f;
            s42 += (c == 2) ? a : 0.f;
            s43 += (c == 3) ? a : 0.f;
        }
        sb_s[(h * NJ + i) * 4 + 0] = s40;
        sb_s[(h * NJ + i) * 4 + 1] = s41;
        sb_s[(h * NJ + i) * 4 + 2] = s42;
        sb_s[(h * NJ + i) * 4 + 3] = s43;
    }
    __syncthreads();

    for (int e = tid; e < HEADS * NJ * (DEPTH / 2); e += 256) {  // 4608 pairs
        int h = e / (NJ * (DEPTH / 2));
        int r = e - h * (NJ * (DEPTH / 2));
        int i = r >> 5, dd = (r & 31) * 2;
        float a0 = 0.f, a1 = 0.f;
        #pragma unroll
        for (int j = 0; j < NJ; ++j) {
            float a = att_s[(h * NJ + i) * NJ + j];
            f16x2 vp = *(const f16x2*)&v_s[j * DIMM + h * DEPTH + dd];
            a0 += a * (float)vp[0];
            a1 += a * (float)vp[1];
        }
        #pragma unroll
        for (int c = 0; c < 4; ++c) {
            float sc = sb_s[(h * NJ + i) * 4 + c];
            a0 += sc * relv_s[c * DEPTH + dd];
            a1 += sc * relv_s[c * DEPTH + dd + 1];
        }
        f16x2 res;
        res[0] = (f16_t)a0;
        res[1] = (f16_t)a1;
        *(f16x2*)(ao + base + i * DIMM + h * DEPTH + dd) = res;
    }
}

// ---------------------------------------------------------------------------
extern "C" void kernel_launch(void* const* d_in, const int* in_sizes, int n_in,
                              void* d_out, int out_size, void* d_ws, size_t ws_size,
                              hipStream_t stream) {
    (void)in_sizes; (void)n_in; (void)out_size; (void)ws_size;
    const float* k_in = (const float*)d_in[0];
    const float* v_in = (const float*)d_in[1];
    const float* q_in = (const float*)d_in[2];
    const float* Wq   = (const float*)d_in[3];
    const float* Wk   = (const float*)d_in[4];
    const float* Wv   = (const float*)d_in[5];
    const float* Wo   = (const float*)d_in[6];
    const float* bo   = (const float*)d_in[7];
    const float* relk = (const float*)d_in[8];
    const float* relv = (const float*)d_in[9];
    const int*   jmap = (const int*)d_in[10];

    char* ws = (char*)d_ws;
    const size_t WT = (size_t)DIMM * DIMM * sizeof(bf16_t);   // 512 KB per plane
    bf16_t* Thq = (bf16_t*)(ws + 0 * WT);
    bf16_t* Tlq = (bf16_t*)(ws + 1 * WT);
    bf16_t* Thk = (bf16_t*)(ws + 2 * WT);
    bf16_t* Tlk = (bf16_t*)(ws + 3 * WT);
    bf16_t* Thv = (bf16_t*)(ws + 4 * WT);
    bf16_t* Tlv = (bf16_t*)(ws + 5 * WT);
    bf16_t* Tho = (bf16_t*)(ws + 6 * WT);
    bf16_t* Tlo = (bf16_t*)(ws + 7 * WT);
    const size_t PSZ = (size_t)MROWS * DIMM * sizeof(f16_t);  // 75.5 MB each
    f16_t* qh = (f16_t*)(ws + 8 * WT + 0 * PSZ);
    f16_t* kh = (f16_t*)(ws + 8 * WT + 1 * PSZ);
    f16_t* vh = (f16_t*)(ws + 8 * WT + 2 * PSZ);
    f16_t* ao = vh;   // alias: attn reads v into LDS before writing ao (barrier)

    float* outp = (float*)d_out;
    float* attp = outp + ATT_OFF;

    split_w_kernel<<<dim3(8, 8, 4), 256, 0, stream>>>(
        Wq, Wk, Wv, Wo, Thq, Tlq, Thk, Tlk, Thv, Tlv, Tho, Tlo);

    dim3 ggrid(DIMM / 128, MROWS / 128);  // (4, 576)
    gemm3_kernel<0><<<ggrid, 256, 0, stream>>>(q_in, Thq, Tlq, qh, nullptr);
    gemm3_kernel<0><<<ggrid, 256, 0, stream>>>(k_in, Thk, Tlk, kh, nullptr);
    gemm3_kernel<0><<<ggrid, 256, 0, stream>>>(v_in, Thv, Tlv, vh, nullptr);

    attn_kernel<<<BATCH, 256, 0, stream>>>(qh, kh, vh, relk, relv, jmap, attp, ao);

    gemm3_kernel<1><<<ggrid, 256, 0, stream>>>(ao, Tho, Tlo, outp, bo);
}

// Round 4
// 522.982 us; speedup vs baseline: 1.5214x; 1.5214x over previous
//
#include <hip/hip_runtime.h>
#include <stdint.h>

#define BATCH 4096
#define NJ 18
#define DIMM 512
#define HEADS 8
#define DEPTH 64
#define MROWS (BATCH*NJ)               // 73728
#define ATT_OFF ((size_t)MROWS*DIMM)   // start of att in d_out (floats)

typedef float f32x4 __attribute__((ext_vector_type(4)));
typedef _Float16 f16_t;
typedef _Float16 f16x2 __attribute__((ext_vector_type(2)));
typedef _Float16 f16x4 __attribute__((ext_vector_type(4)));
typedef _Float16 f16x8 __attribute__((ext_vector_type(8)));

// ---------------------------------------------------------------------------
// Kernel 0: transpose + f16-convert the 4 weights: W[k][n] -> T[n][k]
// ---------------------------------------------------------------------------
__global__ __launch_bounds__(256) void convert_w_kernel(
    const float* __restrict__ W0, const float* __restrict__ W1,
    const float* __restrict__ W2, const float* __restrict__ W3,
    f16_t* __restrict__ T0, f16_t* __restrict__ T1,
    f16_t* __restrict__ T2, f16_t* __restrict__ T3)
{
    const float* W = blockIdx.z == 0 ? W0 : blockIdx.z == 1 ? W1 : blockIdx.z == 2 ? W2 : W3;
    f16_t* T       = blockIdx.z == 0 ? T0 : blockIdx.z == 1 ? T1 : blockIdx.z == 2 ? T2 : T3;
    __shared__ float ld[64][65];
    int k0 = blockIdx.y * 64, n0 = blockIdx.x * 64;
    int tid = threadIdx.x;
    #pragma unroll
    for (int it = 0; it < 16; ++it) {
        int idx = tid + it * 256;
        int kk = idx >> 6, nn = idx & 63;
        ld[kk][nn] = W[(size_t)(k0 + kk) * DIMM + n0 + nn];
    }
    __syncthreads();
    #pragma unroll
    for (int it = 0; it < 16; ++it) {
        int idx = tid + it * 256;
        int nn = idx >> 6, kk = idx & 63;
        T[(size_t)(n0 + nn) * DIMM + k0 + kk] = (f16_t)ld[kk][nn];
    }
}

// ---------------------------------------------------------------------------
// f16 GEMM: C = A @ W, W pre-transposed f16 Bt[n][k]. 128x128 tile, BK=32,
// 4 waves (2x2), per-wave 64x64 via 4x4 of mfma_f32_16x16x32_f16.
// MODE 0: A f32 (selected by blockIdx.z from A0/A1/A2) -> C f16 (C0/C1/C2).
// MODE 1: A f16 (A0) -> C f32 + bias (C0).
// ---------------------------------------------------------------------------
template <int MODE>
__global__ __launch_bounds__(256) void gemm16_kernel(
    const void* __restrict__ A0, const void* __restrict__ A1,
    const void* __restrict__ A2,
    const f16_t* __restrict__ B0, const f16_t* __restrict__ B1,
    const f16_t* __restrict__ B2,
    void* __restrict__ C0, void* __restrict__ C1, void* __restrict__ C2,
    const float* __restrict__ bias)
{
    const void* Aparm = blockIdx.z == 0 ? A0 : blockIdx.z == 1 ? A1 : A2;
    const f16_t* Bt   = blockIdx.z == 0 ? B0 : blockIdx.z == 1 ? B1 : B2;
    void* Cparm       = blockIdx.z == 0 ? C0 : blockIdx.z == 1 ? C1 : C2;

    __shared__ __align__(16) f16_t As[128 * 40];
    __shared__ __align__(16) f16_t Bs[128 * 40];
    const int tid = threadIdx.x;
    const int lane = tid & 63;
    const int wv = tid >> 6;
    const int wm = wv >> 1, wn = wv & 1;
    const int bm = blockIdx.y * 128, bn = blockIdx.x * 128;
    const int l15 = lane & 15, lg = lane >> 4;

    f32x4 acc[4][4] = {};

    for (int ks = 0; ks < DIMM / 32; ++ks) {
        const int k0 = ks * 32;
        __syncthreads();
        #pragma unroll
        for (int r = 0; r < 2; ++r) {
            int c = tid + r * 256;            // 512 chunks of 8 elements
            int row = c >> 2, kc = c & 3;
            f16x8 val;
            if constexpr (MODE == 0) {
                const float* A = (const float*)Aparm;
                const f32x4* p = (const f32x4*)(A + (size_t)(bm + row) * DIMM + k0 + kc * 8);
                f32x4 a0 = p[0], a1 = p[1];
                val[0] = (f16_t)a0[0]; val[1] = (f16_t)a0[1];
                val[2] = (f16_t)a0[2]; val[3] = (f16_t)a0[3];
                val[4] = (f16_t)a1[0]; val[5] = (f16_t)a1[1];
                val[6] = (f16_t)a1[2]; val[7] = (f16_t)a1[3];
            } else {
                const f16_t* A = (const f16_t*)Aparm;
                val = *(const f16x8*)(A + (size_t)(bm + row) * DIMM + k0 + kc * 8);
            }
            *(f16x8*)(&As[row * 40 + kc * 8]) = val;
            f16x8 bv = *(const f16x8*)(Bt + (size_t)(bn + row) * DIMM + k0 + kc * 8);
            *(f16x8*)(&Bs[row * 40 + kc * 8]) = bv;
        }
        __syncthreads();
        f16x8 af[4], bfr[4];
        #pragma unroll
        for (int mi = 0; mi < 4; ++mi)
            af[mi] = *(const f16x8*)(&As[(wm * 64 + mi * 16 + l15) * 40 + lg * 8]);
        #pragma unroll
        for (int ni = 0; ni < 4; ++ni)
            bfr[ni] = *(const f16x8*)(&Bs[(wn * 64 + ni * 16 + l15) * 40 + lg * 8]);
        #pragma unroll
        for (int mi = 0; mi < 4; ++mi)
            #pragma unroll
            for (int ni = 0; ni < 4; ++ni)
                acc[mi][ni] = __builtin_amdgcn_mfma_f32_16x16x32_f16(
                    af[mi], bfr[ni], acc[mi][ni], 0, 0, 0);
    }

    // epilogue: C/D layout col = lane&15, row = (lane>>4)*4 + reg  [HW-verified]
    #pragma unroll
    for (int mi = 0; mi < 4; ++mi) {
        #pragma unroll
        for (int ni = 0; ni < 4; ++ni) {
            int col = bn + wn * 64 + ni * 16 + l15;
            int rowb = bm + wm * 64 + mi * 16 + lg * 4;
            f32x4 v = acc[mi][ni];
            if constexpr (MODE == 1) {
                float* C = (float*)Cparm;
                float bv = bias[col];
                #pragma unroll
                for (int r = 0; r < 4; ++r)
                    C[(size_t)(rowb + r) * DIMM + col] = v[r] + bv;
            } else {
                f16_t* C = (f16_t*)Cparm;
                #pragma unroll
                for (int r = 0; r < 4; ++r)
                    C[(size_t)(rowb + r) * DIMM + col] = (f16_t)v[r];
            }
        }
    }
}

// ---------------------------------------------------------------------------
// Attention core: one block (256 thr) per sample. Fused softmax+PV per thread
// (h,i); k/v in LDS with per-head chunk rotation (conflict-free); q in regs.
// k_s/v_s chunk layout: 16B chunk (j, h, t) stored at j*64 + h*8 + ((t+h)&7).
// ao aliases vh: v fully staged to LDS (barrier) before any ao write. Safe.
// ---------------------------------------------------------------------------
__global__ __launch_bounds__(256, 3) void attn_kernel(
    const f16_t* __restrict__ qh, const f16_t* __restrict__ kh,
    const f16_t* __restrict__ vh,
    const float* __restrict__ rel_k, const float* __restrict__ rel_v,
    const int* __restrict__ jmap,
    float* __restrict__ att_out, f16_t* __restrict__ ao)
{
    const int b = blockIdx.x;
    const int tid = threadIdx.x;
    __shared__ __align__(16) f16_t k_s[NJ * DIMM];
    __shared__ __align__(16) f16_t v_s[NJ * DIMM];
    __shared__ float relk_s[4 * DEPTH];
    __shared__ float relv_s[4 * DEPTH];
    __shared__ int map_s[NJ * NJ];
    __shared__ float ksum_s[NJ * DEPTH];
    __shared__ float t4_s[NJ * 4];

    const size_t base = (size_t)b * (NJ * DIMM);
    const uint4* kg = (const uint4*)(kh + base);
    const uint4* vg = (const uint4*)(vh + base);
    uint4* ks4 = (uint4*)k_s;
    uint4* vs4 = (uint4*)v_s;
    for (int c = tid; c < 2 * NJ * 64; c += 256) {   // 2304 16B chunks
        int t = c / (NJ * 64);
        int e = c - t * (NJ * 64);                   // j*64 + m, m = h*8 + tt
        int m = e & 63;
        int pos = (e & ~63) + (m & 56) + (((m & 7) + (m >> 3)) & 7);
        uint4 val = (t == 0 ? kg : vg)[e];
        (t == 0 ? ks4 : vs4)[pos] = val;
    }
    relk_s[tid & 255] = rel_k[tid & 255];
    relv_s[tid & 255] = rel_v[tid & 255];
    for (int e = tid; e < NJ * NJ; e += 256) map_s[e] = jmap[e];

    // q row for this thread, loaded while staging is in flight
    const int h = tid / NJ, i = tid - (tid / NJ) * NJ;
    const bool act = tid < HEADS * NJ;
    f16x8 qr[8];
    if (act) {
        const f16x8* qp = (const f16x8*)(qh + base + i * DIMM + h * DEPTH);
        #pragma unroll
        for (int t = 0; t < 8; ++t) qr[t] = qp[t];
    }
    __syncthreads();

    const f16x8* ks8 = (const f16x8*)k_s;
    const f16x8* vs8 = (const f16x8*)v_s;

    for (int e = tid; e < NJ * DEPTH; e += 256) {    // ksum[i][d] = sum_h k
        int ii = e >> 6, dd = e & 63;
        int tt = dd >> 3, d7 = dd & 7;
        float s = 0.f;
        #pragma unroll
        for (int hh = 0; hh < HEADS; ++hh)
            s += (float)k_s[((ii << 6) + (hh << 3) + ((tt + hh) & 7)) * 8 + d7];
        ksum_s[e] = s;
    }
    __syncthreads();
    if (tid < NJ * 4) {
        int ii = tid >> 2, c = tid & 3;
        float s = 0.f;
        #pragma unroll
        for (int dd = 0; dd < DEPTH; ++dd)
            s += ksum_s[ii * DEPTH + dd] * relk_s[c * DEPTH + dd];
        t4_s[tid] = s;
    }
    __syncthreads();

    if (!act) return;

    // ---- QK^T + rel bias + softmax (att in registers) ----
    float att[NJ];
    float m = -1e30f;
    #pragma unroll
    for (int j = 0; j < NJ; ++j) {
        float s = 0.f;
        #pragma unroll
        for (int t = 0; t < 8; ++t) {
            f16x8 kv = ks8[(j << 6) + (h << 3) + ((t + h) & 7)];
            f16x8 a = qr[t];
            #pragma unroll
            for (int e = 0; e < 8; ++e) s += (float)a[e] * (float)kv[e];
        }
        s += t4_s[i * 4 + map_s[i * NJ + j]];
        s *= 0.125f;
        att[j] = s;
        m = fmaxf(m, s);
    }
    float sum = 0.f;
    #pragma unroll
    for (int j = 0; j < NJ; ++j) { att[j] = __expf(att[j] - m); sum += att[j]; }
    const float inv = 1.f / sum;
    float s4[4] = {0.f, 0.f, 0.f, 0.f};
    float* ap = att_out + (((size_t)b * HEADS + h) * NJ + i) * NJ;
    #pragma unroll
    for (int j = 0; j < NJ; ++j) {
        float a = att[j] * inv;
        att[j] = a;
        ap[j] = a;
        int c = map_s[i * NJ + j];
        s4[0] += (c == 0) ? a : 0.f;
        s4[1] += (c == 1) ? a : 0.f;
        s4[2] += (c == 2) ? a : 0.f;
        s4[3] += (c == 3) ? a : 0.f;
    }

    // ---- fused PV + rel_v, 32 outputs at a time ----
    f16x8* aop = (f16x8*)(ao + base + i * DIMM + h * DEPTH);
    #pragma unroll
    for (int half = 0; half < 2; ++half) {
        float acc[32] = {};
        #pragma unroll
        for (int j = 0; j < NJ; ++j) {
            float a = att[j];
            #pragma unroll
            for (int t = 0; t < 4; ++t) {
                int tt = half * 4 + t;
                f16x8 vv = vs8[(j << 6) + (h << 3) + ((tt + h) & 7)];
                #pragma unroll
                for (int e = 0; e < 8; ++e) acc[t * 8 + e] += a * (float)vv[e];
            }
        }
        #pragma unroll
        for (int c = 0; c < 4; ++c) {
            float sc = s4[c];
            #pragma unroll
            for (int d = 0; d < 32; ++d)
                acc[d] += sc * relv_s[c * DEPTH + half * 32 + d];
        }
        #pragma unroll
        for (int t = 0; t < 4; ++t) {
            f16x8 res;
            #pragma unroll
            for (int e = 0; e < 8; ++e) res[e] = (f16_t)acc[t * 8 + e];
            aop[half * 4 + t] = res;
        }
    }
}

// ---------------------------------------------------------------------------
extern "C" void kernel_launch(void* const* d_in, const int* in_sizes, int n_in,
                              void* d_out, int out_size, void* d_ws, size_t ws_size,
                              hipStream_t stream) {
    (void)in_sizes; (void)n_in; (void)out_size; (void)ws_size;
    const float* k_in = (const float*)d_in[0];
    const float* v_in = (const float*)d_in[1];
    const float* q_in = (const float*)d_in[2];
    const float* Wq   = (const float*)d_in[3];
    const float* Wk   = (const float*)d_in[4];
    const float* Wv   = (const float*)d_in[5];
    const float* Wo   = (const float*)d_in[6];
    const float* bo   = (const float*)d_in[7];
    const float* relk = (const float*)d_in[8];
    const float* relv = (const float*)d_in[9];
    const int*   jmap = (const int*)d_in[10];

    char* ws = (char*)d_ws;
    const size_t WT = (size_t)DIMM * DIMM * sizeof(f16_t);    // 512 KB each
    f16_t* Tq = (f16_t*)(ws + 0 * WT);
    f16_t* Tk = (f16_t*)(ws + 1 * WT);
    f16_t* Tv = (f16_t*)(ws + 2 * WT);
    f16_t* To = (f16_t*)(ws + 3 * WT);
    const size_t PSZ = (size_t)MROWS * DIMM * sizeof(f16_t);  // 75.5 MB each
    f16_t* qh = (f16_t*)(ws + 4 * WT + 0 * PSZ);
    f16_t* kh = (f16_t*)(ws + 4 * WT + 1 * PSZ);
    f16_t* vh = (f16_t*)(ws + 4 * WT + 2 * PSZ);
    f16_t* ao = vh;   // alias: v fully staged to LDS before ao writes (barrier)

    float* outp = (float*)d_out;
    float* attp = outp + ATT_OFF;

    convert_w_kernel<<<dim3(8, 8, 4), 256, 0, stream>>>(
        Wq, Wk, Wv, Wo, Tq, Tk, Tv, To);

    gemm16_kernel<0><<<dim3(DIMM / 128, MROWS / 128, 3), 256, 0, stream>>>(
        q_in, k_in, v_in, Tq, Tk, Tv, qh, kh, vh, nullptr);

    attn_kernel<<<BATCH, 256, 0, stream>>>(qh, kh, vh, relk, relv, jmap, attp, ao);

    gemm16_kernel<1><<<dim3(DIMM / 128, MROWS / 128, 1), 256, 0, stream>>>(
        ao, nullptr, nullptr, To, nullptr, nullptr, outp, nullptr, nullptr, bo);
}

// Round 5
// 485.867 us; speedup vs baseline: 1.6376x; 1.0764x over previous
//
#include <hip/hip_runtime.h>
#include <stdint.h>

#define BATCH 4096
#define NJ 18
#define DIMM 512
#define HEADS 8
#define DEPTH 64
#define MROWS (BATCH*NJ)               // 73728
#define ATT_OFF ((size_t)MROWS*DIMM)   // start of att in d_out (floats)
#define LDSP 44                        // LDS row stride (f16): 22 dwords, conflict-free

typedef float f32x4 __attribute__((ext_vector_type(4)));
typedef _Float16 f16_t;
typedef _Float16 f16x2 __attribute__((ext_vector_type(2)));
typedef _Float16 f16x4 __attribute__((ext_vector_type(4)));
typedef _Float16 f16x8 __attribute__((ext_vector_type(8)));

// ---------------------------------------------------------------------------
// Kernel 0: transpose + f16-convert the 4 weights: W[k][n] -> T[n][k]
// ---------------------------------------------------------------------------
__global__ __launch_bounds__(256) void convert_w_kernel(
    const float* __restrict__ W0, const float* __restrict__ W1,
    const float* __restrict__ W2, const float* __restrict__ W3,
    f16_t* __restrict__ T0, f16_t* __restrict__ T1,
    f16_t* __restrict__ T2, f16_t* __restrict__ T3)
{
    const float* W = blockIdx.z == 0 ? W0 : blockIdx.z == 1 ? W1 : blockIdx.z == 2 ? W2 : W3;
    f16_t* T       = blockIdx.z == 0 ? T0 : blockIdx.z == 1 ? T1 : blockIdx.z == 2 ? T2 : T3;
    __shared__ float ld[64][65];
    int k0 = blockIdx.y * 64, n0 = blockIdx.x * 64;
    int tid = threadIdx.x;
    #pragma unroll
    for (int it = 0; it < 16; ++it) {
        int idx = tid + it * 256;
        int kk = idx >> 6, nn = idx & 63;
        ld[kk][nn] = W[(size_t)(k0 + kk) * DIMM + n0 + nn];
    }
    __syncthreads();
    #pragma unroll
    for (int it = 0; it < 16; ++it) {
        int idx = tid + it * 256;
        int nn = idx >> 6, kk = idx & 63;
        T[(size_t)(n0 + nn) * DIMM + k0 + kk] = (f16_t)ld[kk][nn];
    }
}

// ---------------------------------------------------------------------------
// f16 GEMM: C = A @ W, W pre-transposed f16 Bt[n][k]. 128x128 tile, BK=32,
// 4 waves (2x2), per-wave 64x64 via 4x4 of mfma_f32_16x16x32_f16.
// XCD-aware bijective block swizzle: the 4 N-blocks sharing an A row-panel
// get block-ids spaced by 8 -> same XCD L2 -> A fetched once per panel.
// MODE 0: A f32 (blockIdx.z selects A0/A1/A2) -> C f16. MODE 1: A f16 -> f32+bias.
// ---------------------------------------------------------------------------
template <int MODE>
__global__ __launch_bounds__(256) void gemm16_kernel(
    const void* __restrict__ A0, const void* __restrict__ A1,
    const void* __restrict__ A2,
    const f16_t* __restrict__ B0, const f16_t* __restrict__ B1,
    const f16_t* __restrict__ B2,
    void* __restrict__ C0, void* __restrict__ C1, void* __restrict__ C2,
    const float* __restrict__ bias)
{
    const void* Aparm = blockIdx.z == 0 ? A0 : blockIdx.z == 1 ? A1 : A2;
    const f16_t* Bt   = blockIdx.z == 0 ? B0 : blockIdx.z == 1 ? B1 : B2;
    void* Cparm       = blockIdx.z == 0 ? C0 : blockIdx.z == 1 ? C1 : C2;

    // XCD swizzle (nwg = 2304 per z-slice, 2304 % 8 == 0 -> simple bijection)
    const int p = blockIdx.x + (DIMM / 128) * blockIdx.y;
    const int logical = (p & 7) * ((DIMM / 128) * (MROWS / 128) / 8) + (p >> 3);
    const int bn = (logical & 3) * 128;
    const int bm = (logical >> 2) * 128;

    __shared__ __align__(16) f16_t As[128 * LDSP];
    __shared__ __align__(16) f16_t Bs[128 * LDSP];
    const int tid = threadIdx.x;
    const int lane = tid & 63;
    const int wv = tid >> 6;
    const int wm = wv >> 1, wn = wv & 1;
    const int l15 = lane & 15, lg = lane >> 4;

    f32x4 acc[4][4] = {};

    for (int ks = 0; ks < DIMM / 32; ++ks) {
        const int k0 = ks * 32;
        __syncthreads();
        #pragma unroll
        for (int r = 0; r < 2; ++r) {
            int c = tid + r * 256;            // 512 chunks of 8 elements
            int row = c >> 2, kc = c & 3;
            f16x8 val;
            if constexpr (MODE == 0) {
                const float* A = (const float*)Aparm;
                const f32x4* p4 = (const f32x4*)(A + (size_t)(bm + row) * DIMM + k0 + kc * 8);
                f32x4 a0 = p4[0], a1 = p4[1];
                val[0] = (f16_t)a0[0]; val[1] = (f16_t)a0[1];
                val[2] = (f16_t)a0[2]; val[3] = (f16_t)a0[3];
                val[4] = (f16_t)a1[0]; val[5] = (f16_t)a1[1];
                val[6] = (f16_t)a1[2]; val[7] = (f16_t)a1[3];
            } else {
                const f16_t* A = (const f16_t*)Aparm;
                val = *(const f16x8*)(A + (size_t)(bm + row) * DIMM + k0 + kc * 8);
            }
            *(f16x8*)(&As[row * LDSP + kc * 8]) = val;
            f16x8 bv = *(const f16x8*)(Bt + (size_t)(bn + row) * DIMM + k0 + kc * 8);
            *(f16x8*)(&Bs[row * LDSP + kc * 8]) = bv;
        }
        __syncthreads();
        f16x8 af[4], bfr[4];
        #pragma unroll
        for (int mi = 0; mi < 4; ++mi)
            af[mi] = *(const f16x8*)(&As[(wm * 64 + mi * 16 + l15) * LDSP + lg * 8]);
        #pragma unroll
        for (int ni = 0; ni < 4; ++ni)
            bfr[ni] = *(const f16x8*)(&Bs[(wn * 64 + ni * 16 + l15) * LDSP + lg * 8]);
        #pragma unroll
        for (int mi = 0; mi < 4; ++mi)
            #pragma unroll
            for (int ni = 0; ni < 4; ++ni)
                acc[mi][ni] = __builtin_amdgcn_mfma_f32_16x16x32_f16(
                    af[mi], bfr[ni], acc[mi][ni], 0, 0, 0);
    }

    // epilogue: C/D layout col = lane&15, row = (lane>>4)*4 + reg  [HW-verified]
    #pragma unroll
    for (int mi = 0; mi < 4; ++mi) {
        #pragma unroll
        for (int ni = 0; ni < 4; ++ni) {
            int col = bn + wn * 64 + ni * 16 + l15;
            int rowb = bm + wm * 64 + mi * 16 + lg * 4;
            f32x4 v = acc[mi][ni];
            if constexpr (MODE == 1) {
                float* C = (float*)Cparm;
                float bv = bias[col];
                #pragma unroll
                for (int r = 0; r < 4; ++r)
                    C[(size_t)(rowb + r) * DIMM + col] = v[r] + bv;
            } else {
                f16_t* C = (f16_t*)Cparm;
                #pragma unroll
                for (int r = 0; r < 4; ++r)
                    C[(size_t)(rowb + r) * DIMM + col] = (f16_t)v[r];
            }
        }
    }
}

// ---------------------------------------------------------------------------
// Attention core: one block (256 thr) per sample. Fused softmax+PV per thread
// (h,i); k/v in LDS with per-head chunk rotation (conflict-free); q in regs.
// k_s/v_s chunk layout: 16B chunk (j, h, t) stored at j*64 + h*8 + ((t+h)&7).
// ao aliases vh: v fully staged to LDS (barrier) before any ao write. Safe.
// ---------------------------------------------------------------------------
__global__ __launch_bounds__(256, 3) void attn_kernel(
    const f16_t* __restrict__ qh, const f16_t* __restrict__ kh,
    const f16_t* __restrict__ vh,
    const float* __restrict__ rel_k, const float* __restrict__ rel_v,
    const int* __restrict__ jmap,
    float* __restrict__ att_out, f16_t* __restrict__ ao)
{
    const int b = blockIdx.x;
    const int tid = threadIdx.x;
    __shared__ __align__(16) f16_t k_s[NJ * DIMM];
    __shared__ __align__(16) f16_t v_s[NJ * DIMM];
    __shared__ float relk_s[4 * DEPTH];
    __shared__ float relv_s[4 * DEPTH];
    __shared__ int map_s[NJ * NJ];
    __shared__ float ksum_s[NJ * DEPTH];
    __shared__ float t4_s[NJ * 4];

    const size_t base = (size_t)b * (NJ * DIMM);
    const uint4* kg = (const uint4*)(kh + base);
    const uint4* vg = (const uint4*)(vh + base);
    uint4* ks4 = (uint4*)k_s;
    uint4* vs4 = (uint4*)v_s;
    for (int c = tid; c < 2 * NJ * 64; c += 256) {   // 2304 16B chunks
        int t = c / (NJ * 64);
        int e = c - t * (NJ * 64);                   // j*64 + m, m = h*8 + tt
        int m = e & 63;
        int pos = (e & ~63) + (m & 56) + (((m & 7) + (m >> 3)) & 7);
        uint4 val = (t == 0 ? kg : vg)[e];
        (t == 0 ? ks4 : vs4)[pos] = val;
    }
    relk_s[tid & 255] = rel_k[tid & 255];
    relv_s[tid & 255] = rel_v[tid & 255];
    for (int e = tid; e < NJ * NJ; e += 256) map_s[e] = jmap[e];

    // q row for this thread, loaded while staging is in flight
    const int h = tid / NJ, i = tid - (tid / NJ) * NJ;
    const bool act = tid < HEADS * NJ;
    f16x8 qr[8];
    if (act) {
        const f16x8* qp = (const f16x8*)(qh + base + i * DIMM + h * DEPTH);
        #pragma unroll
        for (int t = 0; t < 8; ++t) qr[t] = qp[t];
    }
    __syncthreads();

    const f16x8* ks8 = (const f16x8*)k_s;
    const f16x8* vs8 = (const f16x8*)v_s;

    for (int e = tid; e < NJ * DEPTH; e += 256) {    // ksum[i][d] = sum_h k
        int ii = e >> 6, dd = e & 63;
        int tt = dd >> 3, d7 = dd & 7;
        float s = 0.f;
        #pragma unroll
        for (int hh = 0; hh < HEADS; ++hh)
            s += (float)k_s[((ii << 6) + (hh << 3) + ((tt + hh) & 7)) * 8 + d7];
        ksum_s[e] = s;
    }
    __syncthreads();
    if (tid < NJ * 4) {
        int ii = tid >> 2, c = tid & 3;
        float s = 0.f;
        #pragma unroll
        for (int dd = 0; dd < DEPTH; ++dd)
            s += ksum_s[ii * DEPTH + dd] * relk_s[c * DEPTH + dd];
        t4_s[tid] = s;
    }
    __syncthreads();

    if (!act) return;

    // ---- QK^T + rel bias + softmax (att in registers) ----
    float att[NJ];
    float m = -1e30f;
    #pragma unroll
    for (int j = 0; j < NJ; ++j) {
        float s = 0.f;
        #pragma unroll
        for (int t = 0; t < 8; ++t) {
            f16x8 kv = ks8[(j << 6) + (h << 3) + ((t + h) & 7)];
            f16x8 a = qr[t];
            #pragma unroll
            for (int e = 0; e < 8; ++e) s += (float)a[e] * (float)kv[e];
        }
        s += t4_s[i * 4 + map_s[i * NJ + j]];
        s *= 0.125f;
        att[j] = s;
        m = fmaxf(m, s);
    }
    float sum = 0.f;
    #pragma unroll
    for (int j = 0; j < NJ; ++j) { att[j] = __expf(att[j] - m); sum += att[j]; }
    const float inv = 1.f / sum;
    float s4[4] = {0.f, 0.f, 0.f, 0.f};
    float* ap = att_out + (((size_t)b * HEADS + h) * NJ + i) * NJ;
    #pragma unroll
    for (int j = 0; j < NJ; ++j) {
        float a = att[j] * inv;
        att[j] = a;
        ap[j] = a;
        int c = map_s[i * NJ + j];
        s4[0] += (c == 0) ? a : 0.f;
        s4[1] += (c == 1) ? a : 0.f;
        s4[2] += (c == 2) ? a : 0.f;
        s4[3] += (c == 3) ? a : 0.f;
    }

    // ---- fused PV + rel_v, 32 outputs at a time ----
    f16x8* aop = (f16x8*)(ao + base + i * DIMM + h * DEPTH);
    #pragma unroll
    for (int half = 0; half < 2; ++half) {
        float acc[32] = {};
        #pragma unroll
        for (int j = 0; j < NJ; ++j) {
            float a = att[j];
            #pragma unroll
            for (int t = 0; t < 4; ++t) {
                int tt = half * 4 + t;
                f16x8 vv = vs8[(j << 6) + (h << 3) + ((tt + h) & 7)];
                #pragma unroll
                for (int e = 0; e < 8; ++e) acc[t * 8 + e] += a * (float)vv[e];
            }
        }
        #pragma unroll
        for (int c = 0; c < 4; ++c) {
            float sc = s4[c];
            #pragma unroll
            for (int d = 0; d < 32; ++d)
                acc[d] += sc * relv_s[c * DEPTH + half * 32 + d];
        }
        #pragma unroll
        for (int t = 0; t < 4; ++t) {
            f16x8 res;
            #pragma unroll
            for (int e = 0; e < 8; ++e) res[e] = (f16_t)acc[t * 8 + e];
            aop[half * 4 + t] = res;
        }
    }
}

// ---------------------------------------------------------------------------
extern "C" void kernel_launch(void* const* d_in, const int* in_sizes, int n_in,
                              void* d_out, int out_size, void* d_ws, size_t ws_size,
                              hipStream_t stream) {
    (void)in_sizes; (void)n_in; (void)out_size; (void)ws_size;
    const float* k_in = (const float*)d_in[0];
    const float* v_in = (const float*)d_in[1];
    const float* q_in = (const float*)d_in[2];
    const float* Wq   = (const float*)d_in[3];
    const float* Wk   = (const float*)d_in[4];
    const float* Wv   = (const float*)d_in[5];
    const float* Wo   = (const float*)d_in[6];
    const float* bo   = (const float*)d_in[7];
    const float* relk = (const float*)d_in[8];
    const float* relv = (const float*)d_in[9];
    const int*   jmap = (const int*)d_in[10];

    char* ws = (char*)d_ws;
    const size_t WT = (size_t)DIMM * DIMM * sizeof(f16_t);    // 512 KB each
    f16_t* Tq = (f16_t*)(ws + 0 * WT);
    f16_t* Tk = (f16_t*)(ws + 1 * WT);
    f16_t* Tv = (f16_t*)(ws + 2 * WT);
    f16_t* To = (f16_t*)(ws + 3 * WT);
    const size_t PSZ = (size_t)MROWS * DIMM * sizeof(f16_t);  // 75.5 MB each
    f16_t* qh = (f16_t*)(ws + 4 * WT + 0 * PSZ);
    f16_t* kh = (f16_t*)(ws + 4 * WT + 1 * PSZ);
    f16_t* vh = (f16_t*)(ws + 4 * WT + 2 * PSZ);
    f16_t* ao = vh;   // alias: v fully staged to LDS before ao writes (barrier)

    float* outp = (float*)d_out;
    float* attp = outp + ATT_OFF;

    convert_w_kernel<<<dim3(8, 8, 4), 256, 0, stream>>>(
        Wq, Wk, Wv, Wo, Tq, Tk, Tv, To);

    gemm16_kernel<0><<<dim3(DIMM / 128, MROWS / 128, 3), 256, 0, stream>>>(
        q_in, k_in, v_in, Tq, Tk, Tv, qh, kh, vh, nullptr);

    attn_kernel<<<BATCH, 256, 0, stream>>>(qh, kh, vh, relk, relv, jmap, attp, ao);

    gemm16_kernel<1><<<dim3(DIMM / 128, MROWS / 128, 1), 256, 0, stream>>>(
        ao, nullptr, nullptr, To, nullptr, nullptr, outp, nullptr, nullptr, bo);
}

// Round 6
// 447.816 us; speedup vs baseline: 1.7768x; 1.0850x over previous
//
#include <hip/hip_runtime.h>
#include <stdint.h>

#define BATCH 4096
#define NJ 18
#define DIMM 512
#define HEADS 8
#define DEPTH 64
#define MROWS (BATCH*NJ)               // 73728
#define ATT_OFF ((size_t)MROWS*DIMM)   // start of att in d_out (floats)

typedef float f32x4 __attribute__((ext_vector_type(4)));
typedef _Float16 f16_t;
typedef _Float16 f16x8 __attribute__((ext_vector_type(8)));

// global -> LDS direct copy, 16 B per lane. LDS dest is wave-uniform base
// + lane*16 (linear); global src is per-lane. (CK-style generic-ptr form.)
__device__ __forceinline__ void gl_lds16(const unsigned int* g, unsigned int* l) {
    __builtin_amdgcn_global_load_lds(g, l, 16, 0, 0);
}

// ---------------------------------------------------------------------------
// Kernel 0: W[k][n] (f32) -> tiled+swizzled f16 image T.
// Tile (nb, ks) = rows nb*128..+127, k ks*64..+63, one contiguous 16 KB chunk
// laid out exactly as the GEMM's LDS image:
//   f16x8 group gk (=k-within-step/8) of row rr stored at vec idx
//   (nb*8+ks)*1024 + rr*8 + (gk ^ (rr&7))   [T2 XOR swizzle baked into source]
// ---------------------------------------------------------------------------
__global__ __launch_bounds__(256) void convert_w_kernel(
    const float* __restrict__ W0, const float* __restrict__ W1,
    const float* __restrict__ W2, const float* __restrict__ W3,
    f16_t* __restrict__ T0, f16_t* __restrict__ T1,
    f16_t* __restrict__ T2, f16_t* __restrict__ T3)
{
    const float* W = blockIdx.z == 0 ? W0 : blockIdx.z == 1 ? W1 : blockIdx.z == 2 ? W2 : W3;
    f16_t* T       = blockIdx.z == 0 ? T0 : blockIdx.z == 1 ? T1 : blockIdx.z == 2 ? T2 : T3;
    __shared__ float ld[64][65];
    int k0 = blockIdx.y * 64, n0 = blockIdx.x * 64;
    int tid = threadIdx.x;
    #pragma unroll
    for (int it = 0; it < 16; ++it) {
        int idx = tid + it * 256;
        int kk = idx >> 6, nn = idx & 63;
        ld[kk][nn] = W[(size_t)(k0 + kk) * DIMM + n0 + nn];
    }
    __syncthreads();
    f16x8* T8 = (f16x8*)T;
    #pragma unroll
    for (int it = 0; it < 2; ++it) {
        int c = tid + it * 256;            // 512 f16x8 chunks per 64x64 tile
        int nn = c >> 3, c8 = c & 7;
        int n = n0 + nn, k = k0 + c8 * 8;
        f16x8 val;
        #pragma unroll
        for (int e = 0; e < 8; ++e) val[e] = (f16_t)ld[c8 * 8 + e][nn];
        size_t vi = (size_t)((n >> 7) * 8 + (k >> 6)) * 1024
                  + (n & 127) * 8 + (((k >> 3) & 7) ^ (n & 7));
        T8[vi] = val;
    }
}

// ---------------------------------------------------------------------------
// f16 GEMM: C = A @ W. 128x128 tile, BK=64, 4 waves (2x2), per-wave 64x64 via
// 4x4x2 of mfma_f32_16x16x32_f16. B staged via global_load_lds from the
// pre-tiled/pre-swizzled weight image (linear LDS dest, XOR-swizzled reads).
// MODE 0: A f32 row-major (z selects q/k/v), reg-staged+converted, padded LDS.
// MODE 1: A f16 pre-tiled (ao), BOTH operands via global_load_lds. +bias, f32 C.
// XCD-aware bijective block swizzle (2304 blocks/slice, 2304%8==0).
// ---------------------------------------------------------------------------
template <int MODE>
__global__ __launch_bounds__(256) void gemm16_kernel(
    const void* __restrict__ A0, const void* __restrict__ A1,
    const void* __restrict__ A2,
    const f16_t* __restrict__ B0, const f16_t* __restrict__ B1,
    const f16_t* __restrict__ B2,
    void* __restrict__ C0, void* __restrict__ C1, void* __restrict__ C2,
    const float* __restrict__ bias)
{
    const void* Aparm = blockIdx.z == 0 ? A0 : blockIdx.z == 1 ? A1 : A2;
    const f16_t* Bt   = blockIdx.z == 0 ? B0 : blockIdx.z == 1 ? B1 : B2;
    void* Cparm       = blockIdx.z == 0 ? C0 : blockIdx.z == 1 ? C1 : C2;

    const int p = blockIdx.x + 4 * blockIdx.y;
    const int logical = (p & 7) * (2304 / 8) + (p >> 3);
    const int bn = (logical & 3) * 128;
    const int bm = (logical >> 2) * 128;

    __shared__ __align__(16) f16_t As[MODE == 0 ? 128 * 72 : 128 * 64];
    __shared__ __align__(16) f16_t Bs[128 * 64];

    const int tid = threadIdx.x;
    const int lane = tid & 63;
    const int wv = tid >> 6;
    const int wm = wv >> 1, wn = wv & 1;
    const int l15 = lane & 15, lg = lane >> 4;
    const int swz = (l15 & 7) << 4;              // byte XOR mask for this lane
    const int koffb[2] = { (lg * 16) ^ swz, (lg * 16 + 64) ^ swz };

    f32x4 acc[4][4] = {};

    for (int ks = 0; ks < 8; ++ks) {
        __syncthreads();
        {   // B: 16 KB tile via global_load_lds (contiguous source)
            const unsigned int* btile =
                (const unsigned int*)(Bt + (size_t)((bn >> 7) * 8 + ks) * 8192);
            unsigned int* bs = (unsigned int*)Bs;
            #pragma unroll
            for (int it = 0; it < 4; ++it) {
                int chunk = wv * 4 + it;
                gl_lds16(btile + chunk * 256 + lane * 4, bs + chunk * 256);
            }
        }
        if constexpr (MODE == 0) {
            const float* A = (const float*)Aparm;
            #pragma unroll
            for (int r = 0; r < 4; ++r) {
                int c = tid + r * 256;           // 1024 chunks of 8 f32
                int row = c >> 3, kc = c & 7;
                const f32x4* p4 = (const f32x4*)(A + (size_t)(bm + row) * DIMM + ks * 64 + kc * 8);
                f32x4 a0 = p4[0], a1 = p4[1];
                f16x8 val;
                val[0] = (f16_t)a0[0]; val[1] = (f16_t)a0[1];
                val[2] = (f16_t)a0[2]; val[3] = (f16_t)a0[3];
                val[4] = (f16_t)a1[0]; val[5] = (f16_t)a1[1];
                val[6] = (f16_t)a1[2]; val[7] = (f16_t)a1[3];
                *(f16x8*)(&As[row * 72 + kc * 8]) = val;
            }
        } else {
            const unsigned int* atile =
                (const unsigned int*)((const f16_t*)Aparm + (size_t)((bm >> 7) * 8 + ks) * 8192);
            unsigned int* as = (unsigned int*)As;
            #pragma unroll
            for (int it = 0; it < 4; ++it) {
                int chunk = wv * 4 + it;
                gl_lds16(atile + chunk * 256 + lane * 4, as + chunk * 256);
            }
        }
        __syncthreads();

        #pragma unroll
        for (int kk = 0; kk < 2; ++kk) {
            const int koff = koffb[kk];
            f16x8 af[4], bfr[4];
            #pragma unroll
            for (int mi = 0; mi < 4; ++mi) {
                int row = wm * 64 + mi * 16 + l15;
                if constexpr (MODE == 0)
                    af[mi] = *(const f16x8*)(&As[row * 72 + kk * 32 + lg * 8]);
                else
                    af[mi] = *(const f16x8*)((const char*)As + row * 128 + koff);
            }
            #pragma unroll
            for (int ni = 0; ni < 4; ++ni) {
                int row = wn * 64 + ni * 16 + l15;
                bfr[ni] = *(const f16x8*)((const char*)Bs + row * 128 + koff);
            }
            #pragma unroll
            for (int mi = 0; mi < 4; ++mi)
                #pragma unroll
                for (int ni = 0; ni < 4; ++ni)
                    acc[mi][ni] = __builtin_amdgcn_mfma_f32_16x16x32_f16(
                        af[mi], bfr[ni], acc[mi][ni], 0, 0, 0);
        }
    }

    // epilogue: C/D layout col = lane&15, row = (lane>>4)*4 + reg  [HW-verified]
    #pragma unroll
    for (int mi = 0; mi < 4; ++mi) {
        #pragma unroll
        for (int ni = 0; ni < 4; ++ni) {
            int col = bn + wn * 64 + ni * 16 + l15;
            int rowb = bm + wm * 64 + mi * 16 + lg * 4;
            f32x4 v = acc[mi][ni];
            if constexpr (MODE == 1) {
                float* C = (float*)Cparm;
                float bv = bias[col];
                #pragma unroll
                for (int r = 0; r < 4; ++r)
                    C[(size_t)(rowb + r) * DIMM + col] = v[r] + bv;
            } else {
                f16_t* C = (f16_t*)Cparm;
                #pragma unroll
                for (int r = 0; r < 4; ++r)
                    C[(size_t)(rowb + r) * DIMM + col] = (f16_t)v[r];
            }
        }
    }
}

// ---------------------------------------------------------------------------
// Attention core: one block (256 thr) per sample. Fused softmax+PV per thread
// (h,i); k/v in LDS with per-head chunk rotation (conflict-free); q in regs.
// ao written in the GEMM's tiled+swizzled layout (ks == h since DEPTH==64):
//   f16x8 group gk of global row R at vec ((R>>7)*8+h)*1024 + (R&127)*8 + (gk^(R&7))
// ---------------------------------------------------------------------------
__global__ __launch_bounds__(256, 3) void attn_kernel(
    const f16_t* __restrict__ qh, const f16_t* __restrict__ kh,
    const f16_t* __restrict__ vh,
    const float* __restrict__ rel_k, const float* __restrict__ rel_v,
    const int* __restrict__ jmap,
    float* __restrict__ att_out, f16_t* __restrict__ ao)
{
    const int b = blockIdx.x;
    const int tid = threadIdx.x;
    __shared__ __align__(16) f16_t k_s[NJ * DIMM];
    __shared__ __align__(16) f16_t v_s[NJ * DIMM];
    __shared__ float relk_s[4 * DEPTH];
    __shared__ float relv_s[4 * DEPTH];
    __shared__ int map_s[NJ * NJ];
    __shared__ float ksum_s[NJ * DEPTH];
    __shared__ float t4_s[NJ * 4];

    const size_t base = (size_t)b * (NJ * DIMM);
    const uint4* kg = (const uint4*)(kh + base);
    const uint4* vg = (const uint4*)(vh + base);
    uint4* ks4 = (uint4*)k_s;
    uint4* vs4 = (uint4*)v_s;
    for (int c = tid; c < 2 * NJ * 64; c += 256) {   // 2304 16B chunks
        int t = c / (NJ * 64);
        int e = c - t * (NJ * 64);                   // j*64 + m, m = h*8 + tt
        int m = e & 63;
        int pos = (e & ~63) + (m & 56) + (((m & 7) + (m >> 3)) & 7);
        uint4 val = (t == 0 ? kg : vg)[e];
        (t == 0 ? ks4 : vs4)[pos] = val;
    }
    relk_s[tid & 255] = rel_k[tid & 255];
    relv_s[tid & 255] = rel_v[tid & 255];
    for (int e = tid; e < NJ * NJ; e += 256) map_s[e] = jmap[e];

    const int h = tid / NJ, i = tid - (tid / NJ) * NJ;
    const bool act = tid < HEADS * NJ;
    f16x8 qr[8];
    if (act) {
        const f16x8* qp = (const f16x8*)(qh + base + i * DIMM + h * DEPTH);
        #pragma unroll
        for (int t = 0; t < 8; ++t) qr[t] = qp[t];
    }
    __syncthreads();

    const f16x8* ks8 = (const f16x8*)k_s;
    const f16x8* vs8 = (const f16x8*)v_s;

    for (int e = tid; e < NJ * DEPTH; e += 256) {    // ksum[i][d] = sum_h k
        int ii = e >> 6, dd = e & 63;
        int tt = dd >> 3, d7 = dd & 7;
        float s = 0.f;
        #pragma unroll
        for (int hh = 0; hh < HEADS; ++hh)
            s += (float)k_s[((ii << 6) + (hh << 3) + ((tt + hh) & 7)) * 8 + d7];
        ksum_s[e] = s;
    }
    __syncthreads();
    if (tid < NJ * 4) {
        int ii = tid >> 2, c = tid & 3;
        float s = 0.f;
        #pragma unroll
        for (int dd = 0; dd < DEPTH; ++dd)
            s += ksum_s[ii * DEPTH + dd] * relk_s[c * DEPTH + dd];
        t4_s[tid] = s;
    }
    __syncthreads();

    if (!act) return;

    // ---- QK^T + rel bias + softmax (att in registers) ----
    float att[NJ];
    float m = -1e30f;
    #pragma unroll
    for (int j = 0; j < NJ; ++j) {
        float s = 0.f;
        #pragma unroll
        for (int t = 0; t < 8; ++t) {
            f16x8 kv = ks8[(j << 6) + (h << 3) + ((t + h) & 7)];
            f16x8 a = qr[t];
            #pragma unroll
            for (int e = 0; e < 8; ++e) s += (float)a[e] * (float)kv[e];
        }
        s += t4_s[i * 4 + map_s[i * NJ + j]];
        s *= 0.125f;
        att[j] = s;
        m = fmaxf(m, s);
    }
    float sum = 0.f;
    #pragma unroll
    for (int j = 0; j < NJ; ++j) { att[j] = __expf(att[j] - m); sum += att[j]; }
    const float inv = 1.f / sum;
    float s4[4] = {0.f, 0.f, 0.f, 0.f};
    float* ap = att_out + (((size_t)b * HEADS + h) * NJ + i) * NJ;
    #pragma unroll
    for (int j = 0; j < NJ; ++j) {
        float a = att[j] * inv;
        att[j] = a;
        ap[j] = a;
        int c = map_s[i * NJ + j];
        s4[0] += (c == 0) ? a : 0.f;
        s4[1] += (c == 1) ? a : 0.f;
        s4[2] += (c == 2) ? a : 0.f;
        s4[3] += (c == 3) ? a : 0.f;
    }

    // ---- fused PV + rel_v; write ao in tiled+swizzled GEMM-A layout ----
    const size_t grow = (size_t)b * NJ + i;
    f16x8* aot = (f16x8*)ao + ((grow >> 7) * 8 + h) * 1024 + (grow & 127) * 8;
    const int rr7 = (int)(grow & 7);
    #pragma unroll
    for (int half = 0; half < 2; ++half) {
        float acc[32] = {};
        #pragma unroll
        for (int j = 0; j < NJ; ++j) {
            float a = att[j];
            #pragma unroll
            for (int t = 0; t < 4; ++t) {
                int tt = half * 4 + t;
                f16x8 vv = vs8[(j << 6) + (h << 3) + ((tt + h) & 7)];
                #pragma unroll
                for (int e = 0; e < 8; ++e) acc[t * 8 + e] += a * (float)vv[e];
            }
        }
        #pragma unroll
        for (int c = 0; c < 4; ++c) {
            float sc = s4[c];
            #pragma unroll
            for (int d = 0; d < 32; ++d)
                acc[d] += sc * relv_s[c * DEPTH + half * 32 + d];
        }
        #pragma unroll
        for (int t = 0; t < 4; ++t) {
            f16x8 res;
            #pragma unroll
            for (int e = 0; e < 8; ++e) res[e] = (f16_t)acc[t * 8 + e];
            aot[(half * 4 + t) ^ rr7] = res;
        }
    }
}

// ---------------------------------------------------------------------------
extern "C" void kernel_launch(void* const* d_in, const int* in_sizes, int n_in,
                              void* d_out, int out_size, void* d_ws, size_t ws_size,
                              hipStream_t stream) {
    (void)in_sizes; (void)n_in; (void)out_size; (void)ws_size;
    const float* k_in = (const float*)d_in[0];
    const float* v_in = (const float*)d_in[1];
    const float* q_in = (const float*)d_in[2];
    const float* Wq   = (const float*)d_in[3];
    const float* Wk   = (const float*)d_in[4];
    const float* Wv   = (const float*)d_in[5];
    const float* Wo   = (const float*)d_in[6];
    const float* bo   = (const float*)d_in[7];
    const float* relk = (const float*)d_in[8];
    const float* relv = (const float*)d_in[9];
    const int*   jmap = (const int*)d_in[10];

    char* ws = (char*)d_ws;
    const size_t WT = (size_t)DIMM * DIMM * sizeof(f16_t);    // 512 KB each
    f16_t* Tq = (f16_t*)(ws + 0 * WT);
    f16_t* Tk = (f16_t*)(ws + 1 * WT);
    f16_t* Tv = (f16_t*)(ws + 2 * WT);
    f16_t* To = (f16_t*)(ws + 3 * WT);
    const size_t PSZ = (size_t)MROWS * DIMM * sizeof(f16_t);  // 75.5 MB each
    f16_t* qh = (f16_t*)(ws + 4 * WT + 0 * PSZ);
    f16_t* kh = (f16_t*)(ws + 4 * WT + 1 * PSZ);
    f16_t* vh = (f16_t*)(ws + 4 * WT + 2 * PSZ);
    f16_t* ao = (f16_t*)(ws + 4 * WT + 3 * PSZ);  // tiled+swizzled layout

    float* outp = (float*)d_out;
    float* attp = outp + ATT_OFF;

    convert_w_kernel<<<dim3(8, 8, 4), 256, 0, stream>>>(
        Wq, Wk, Wv, Wo, Tq, Tk, Tv, To);

    gemm16_kernel<0><<<dim3(DIMM / 128, MROWS / 128, 3), 256, 0, stream>>>(
        q_in, k_in, v_in, Tq, Tk, Tv, qh, kh, vh, nullptr);

    attn_kernel<<<BATCH, 256, 0, stream>>>(qh, kh, vh, relk, relv, jmap, attp, ao);

    gemm16_kernel<1><<<dim3(DIMM / 128, MROWS / 128, 1), 256, 0, stream>>>(
        ao, nullptr, nullptr, To, nullptr, nullptr, outp, nullptr, nullptr, bo);
}